// Round 2
// 958.352 us; speedup vs baseline: 1.0857x; 1.0857x over previous
//
#include <hip/hip_runtime.h>
#include <cstdint>
#include <cstddef>

#define B_SZ 4096
#define KLEN 8192
#define NF   2112
#define MID  264
#define PD   88

typedef _Float16 f16;
typedef _Float16 f16x4 __attribute__((ext_vector_type(4)));
typedef _Float16 f16x8 __attribute__((ext_vector_type(8)));
typedef float    f32x4 __attribute__((ext_vector_type(4)));

__device__ __forceinline__ void gl2lds16(const void* g, void* l) {
    __builtin_amdgcn_global_load_lds(
        (const __attribute__((address_space(1))) void*)g,
        (__attribute__((address_space(3))) void*)l, 16, 0, 0);
}

// ---------------------------------------------------------------------------
// 1) per-row nonzero count -> alpha[row] = 8/(cnt+1); also cast input to f16
__global__ void k_row_prep(const float* __restrict__ x, f16* __restrict__ xh,
                           float* __restrict__ alpha) {
    const int row = blockIdx.x;
    const float* xr = x + (size_t)row * KLEN;
    f16* xhr = xh + (size_t)row * KLEN;
    int cnt = 0;
    for (int j = threadIdx.x * 4; j < KLEN; j += 256 * 4) {
        float4 v = *(const float4*)(xr + j);
        f16x4 h = { (f16)v.x, (f16)v.y, (f16)v.z, (f16)v.w };
        *(f16x4*)(xhr + j) = h;
        cnt += (v.x != 0.f) + (v.y != 0.f) + (v.z != 0.f) + (v.w != 0.f);
    }
    for (int off = 32; off > 0; off >>= 1) cnt += __shfl_down(cnt, off);
    __shared__ int lsum[4];
    if ((threadIdx.x & 63) == 0) lsum[threadIdx.x >> 6] = cnt;
    __syncthreads();
    if (threadIdx.x == 0)
        alpha[row] = 8.0f / (float)(lsum[0] + lsum[1] + lsum[2] + lsum[3] + 1);
}

// 2) both weight matrices -> f16 scaled by 2^13 (exact), one launch
__global__ void k_cvt_w2(const float* __restrict__ wc, const float* __restrict__ ws,
                         f16* __restrict__ whc, f16* __restrict__ whs, int n4) {
    const float* w = blockIdx.y ? ws : wc;
    f16* wh = blockIdx.y ? whs : whc;
    for (int i = blockIdx.x * blockDim.x + threadIdx.x; i < n4; i += gridDim.x * blockDim.x) {
        float4 v = ((const float4*)w)[i];
        f16x4 h = { (f16)(v.x * 8192.f), (f16)(v.y * 8192.f),
                    (f16)(v.z * 8192.f), (f16)(v.w * 8192.f) };
        ((f16x4*)wh)[i] = h;
    }
}

// 3) template^T -> f16 [320][2112] via coalesced 32x32 LDS transpose
__global__ void k_prep_tt(const float* __restrict__ T, f16* __restrict__ tt) {
    __shared__ float tile[32][33];
    const int k0 = blockIdx.x * 32, n0 = blockIdx.y * 32;
    const int tx = threadIdx.x & 31, ty = threadIdx.x >> 5;
    for (int r = ty; r < 32; r += 8) {
        const int k = k0 + r, n = n0 + tx;
        tile[r][tx] = (n < MID) ? T[(size_t)k * MID + n] : 0.f;
    }
    __syncthreads();
    for (int r = ty; r < 32; r += 8) {
        const int n = n0 + r, k = k0 + tx;
        tt[(size_t)n * NF + k] = (f16)tile[tx][r];
    }
}

// 4) G = T^T T  (fp32, split-K with atomics; G pre-zeroed via memset)
__global__ void k_gram(const float* __restrict__ T, float* __restrict__ G) {
    __shared__ float Pp[32][64];
    __shared__ float Qq[32][64];
    const int i0 = blockIdx.x * 64, j0 = blockIdx.y * 64;
    const int tx = threadIdx.x & 15, ty = threadIdx.x >> 4;
    float acc[4][4] = {};
    for (int kc = blockIdx.z * 11; kc < (int)blockIdx.z * 11 + 11; ++kc) {
        const int k0 = kc * 32;
        for (int l = threadIdx.x; l < 32 * 64; l += 256) {
            const int kk = l >> 6, cc = l & 63, kr = k0 + kk;
            Pp[kk][cc] = (i0 + cc < MID) ? T[(size_t)kr * MID + i0 + cc] : 0.f;
            Qq[kk][cc] = (j0 + cc < MID) ? T[(size_t)kr * MID + j0 + cc] : 0.f;
        }
        __syncthreads();
        for (int kk = 0; kk < 32; ++kk) {
            float a_[4], b_[4];
#pragma unroll
            for (int u = 0; u < 4; ++u) a_[u] = Pp[kk][tx * 4 + u];
#pragma unroll
            for (int w = 0; w < 4; ++w) b_[w] = Qq[kk][ty * 4 + w];
#pragma unroll
            for (int u = 0; u < 4; ++u)
#pragma unroll
                for (int w = 0; w < 4; ++w) acc[u][w] += a_[u] * b_[w];
        }
        __syncthreads();
    }
    for (int u = 0; u < 4; ++u) {
        const int gi = i0 + tx * 4 + u;
        if (gi >= MID) continue;
        for (int w = 0; w < 4; ++w) {
            const int gj = j0 + ty * 4 + w;
            if (gj < MID) atomicAdd(&G[(size_t)gi * MID + gj], acc[u][w]);
        }
    }
}

// 5) Fourier GEMM. m97-style single-buffer 2-barrier loop: 32 KB LDS
//    -> 4+ blocks/CU (vs 2 with the old 64 KB double-buffer). Cross-block
//    wave overlap hides the barrier vmcnt drain (m114/m99: explicit dbuf
//    buys nothing at this structure; occupancy does).
//    XCD-chunked bijective swizzle: 1056 blocks % 8 == 0; each XCD gets
//    132 contiguous tiles = 4 A row-panels (8 MB) x all 33 col-tiles.
//    feat = ((A@Wc^T)*a)^2 + ((A@Ws^T)*a)^2.
__global__ __launch_bounds__(256, 4) void k_fourier(
    const f16* __restrict__ A, const f16* __restrict__ Bc, const f16* __restrict__ Bs,
    const float* __restrict__ alpha, f16* __restrict__ feat) {
    __shared__ __align__(16) f16 As[128 * 64];
    __shared__ __align__(16) f16 Bcs[64 * 64];
    __shared__ __align__(16) f16 Bss[64 * 64];
    const int tid = threadIdx.x, lane = tid & 63, wave = tid >> 6;
    const int wm = wave & 1, wn = wave >> 1;

    // XCD-aware chunked swizzle (bijective since 1056 % 8 == 0)
    const int bid = blockIdx.y * 33 + blockIdx.x;        // dispatch order, x fastest
    const int swz = (bid & 7) * 132 + (bid >> 3);
    const int bx = swz % 33, by = swz / 33;
    const int m0 = by * 128, n0 = bx * 64;

    // staging: chunk c = tid + 256*i -> row = (tid>>3)+32*i, swizzled col
    // (tid&7)^((tid>>3)&7)  [row&7 == (tid>>3)&7 since 32*i = 0 mod 8]
    const int srow = tid >> 3;
    const int scol = ((tid & 7) ^ (srow & 7)) << 3;     // in f16 elements
    const f16* gA  = A  + (size_t)(m0 + srow) * KLEN + scol;
    const f16* gBc = Bc + (size_t)(n0 + srow) * KLEN + scol;
    const f16* gBs = Bs + (size_t)(n0 + srow) * KLEN + scol;

#define STAGE_F(kq)                                                               \
    {                                                                             \
        _Pragma("unroll")                                                         \
        for (int i = 0; i < 4; ++i)                                               \
            gl2lds16(gA + (size_t)(32 * i) * KLEN + (kq),                         \
                     (char*)&As[0] + (tid + 256 * i) * 16);                       \
        _Pragma("unroll")                                                         \
        for (int i = 0; i < 2; ++i)                                               \
            gl2lds16(gBc + (size_t)(32 * i) * KLEN + (kq),                        \
                     (char*)&Bcs[0] + (tid + 256 * i) * 16);                      \
        _Pragma("unroll")                                                         \
        for (int i = 0; i < 2; ++i)                                               \
            gl2lds16(gBs + (size_t)(32 * i) * KLEN + (kq),                        \
                     (char*)&Bss[0] + (tid + 256 * i) * 16);                      \
    }

    f32x4 accC[4][2], accS[4][2];
    const f32x4 z4 = {0.f, 0.f, 0.f, 0.f};
#pragma unroll
    for (int i = 0; i < 4; ++i)
#pragma unroll
        for (int j = 0; j < 2; ++j) { accC[i][j] = z4; accS[i][j] = z4; }

    for (int k0 = 0; k0 < KLEN; k0 += 64) {
        if (k0) __syncthreads();                 // compute(k0-64) done; safe to overwrite
        STAGE_F(k0);
        __syncthreads();                         // stage landed (vmcnt drained here)
#pragma unroll
        for (int kk = 0; kk < 2; ++kk) {
            const int chunk0 = kk * 4 + (lane >> 4);
            f16x8 af[4], bcf[2], bsf[2];
#pragma unroll
            for (int mt = 0; mt < 4; ++mt) {
                const int r = wm * 64 + mt * 16 + (lane & 15);
                af[mt] = *(const f16x8*)(&As[0] + r * 64 + ((chunk0 ^ (r & 7)) << 3));
            }
#pragma unroll
            for (int nt = 0; nt < 2; ++nt) {
                const int r = wn * 32 + nt * 16 + (lane & 15);
                const int off = r * 64 + ((chunk0 ^ (r & 7)) << 3);
                bcf[nt] = *(const f16x8*)(&Bcs[0] + off);
                bsf[nt] = *(const f16x8*)(&Bss[0] + off);
            }
#pragma unroll
            for (int mt = 0; mt < 4; ++mt)
#pragma unroll
                for (int nt = 0; nt < 2; ++nt) {
                    accC[mt][nt] = __builtin_amdgcn_mfma_f32_16x16x32_f16(af[mt], bcf[nt], accC[mt][nt], 0, 0, 0);
                    accS[mt][nt] = __builtin_amdgcn_mfma_f32_16x16x32_f16(af[mt], bsf[nt], accS[mt][nt], 0, 0, 0);
                }
        }
    }
#undef STAGE_F
#pragma unroll
    for (int mt = 0; mt < 4; ++mt)
#pragma unroll
        for (int reg = 0; reg < 4; ++reg) {
            const int row = m0 + wm * 64 + mt * 16 + ((lane >> 4) << 2) + reg;
            const float al = alpha[row];
#pragma unroll
            for (int nt = 0; nt < 2; ++nt) {
                const int col = n0 + wn * 32 + nt * 16 + (lane & 15);
                const float xc = accC[mt][nt][reg] * al;
                const float xs = accS[mt][nt][reg] * al;
                feat[(size_t)row * NF + col] = (f16)(xc * xc + xs * xs);
            }
        }
}

// 6) g64 = feat64 @ T  (f16 MFMA, K=2112, N padded 320), double-buffered
__global__ __launch_bounds__(256, 2) void k_ggemm(
    const f16* __restrict__ A, const f16* __restrict__ Bt, float* __restrict__ g64) {
    __shared__ __align__(16) f16 As[2][128 * 64];
    __shared__ __align__(16) f16 Bs_[2][64 * 64];
    const int tid = threadIdx.x, lane = tid & 63, wave = tid >> 6;
    const int wm = wave & 1, wn = wave >> 1;
    const int m0 = blockIdx.y * 128, n0 = blockIdx.x * 64;
    const int srow = tid >> 3;
    const int scol = ((tid & 7) ^ (srow & 7)) << 3;
    const f16* gA = A + (size_t)(m0 + srow) * NF + scol;
    const f16* gB = Bt + (size_t)(n0 + srow) * NF + scol;

#define STAGE_G(buf, kq)                                                          \
    {                                                                             \
        _Pragma("unroll")                                                         \
        for (int i = 0; i < 4; ++i)                                               \
            gl2lds16(gA + (size_t)(32 * i) * NF + (kq),                           \
                     (char*)&As[buf][0] + (tid + 256 * i) * 16);                  \
        _Pragma("unroll")                                                         \
        for (int i = 0; i < 2; ++i)                                               \
            gl2lds16(gB + (size_t)(32 * i) * NF + (kq),                           \
                     (char*)&Bs_[buf][0] + (tid + 256 * i) * 16);                 \
    }

    f32x4 acc[4][2];
    const f32x4 z4 = {0.f, 0.f, 0.f, 0.f};
#pragma unroll
    for (int i = 0; i < 4; ++i)
#pragma unroll
        for (int j = 0; j < 2; ++j) acc[i][j] = z4;

    STAGE_G(0, 0);
    for (int k0 = 0; k0 < NF; k0 += 64) {
        const int cur = (k0 >> 6) & 1;
        __syncthreads();
        if (k0 + 64 < NF) STAGE_G(cur ^ 1, k0 + 64);
#pragma unroll
        for (int kk = 0; kk < 2; ++kk) {
            const int chunk0 = kk * 4 + (lane >> 4);
            f16x8 af[4], bf[2];
#pragma unroll
            for (int mt = 0; mt < 4; ++mt) {
                const int r = wm * 64 + mt * 16 + (lane & 15);
                af[mt] = *(const f16x8*)(&As[cur][0] + r * 64 + ((chunk0 ^ (r & 7)) << 3));
            }
#pragma unroll
            for (int nt = 0; nt < 2; ++nt) {
                const int r = wn * 32 + nt * 16 + (lane & 15);
                bf[nt] = *(const f16x8*)(&Bs_[cur][0] + r * 64 + ((chunk0 ^ (r & 7)) << 3));
            }
#pragma unroll
            for (int mt = 0; mt < 4; ++mt)
#pragma unroll
                for (int nt = 0; nt < 2; ++nt)
                    acc[mt][nt] = __builtin_amdgcn_mfma_f32_16x16x32_f16(af[mt], bf[nt], acc[mt][nt], 0, 0, 0);
        }
    }
#undef STAGE_G
#pragma unroll
    for (int mt = 0; mt < 4; ++mt)
#pragma unroll
        for (int reg = 0; reg < 4; ++reg) {
            const int row = m0 + wm * 64 + mt * 16 + ((lane >> 4) << 2) + reg;
#pragma unroll
            for (int nt = 0; nt < 2; ++nt) {
                const int col = n0 + wn * 32 + nt * 16 + (lane & 15);
                if (col < MID) g64[(size_t)row * MID + col] = acc[mt][nt][reg];
            }
        }
}

// 7) LISTA + MLP + sigmoid, fp32. 8 rows/block (512 blocks = 2/CU for
//    latency hiding). Thread t<264 owns a 2x4 (row,col) micro-tile.
__global__ __launch_bounds__(320) void k_tail(
    const float* __restrict__ g64, const float* __restrict__ Gm,
    const float* __restrict__ W1, const float* __restrict__ b1,
    const float* __restrict__ W2, const float* __restrict__ b2,
    const float* __restrict__ Wout, const float* __restrict__ bout,
    float* __restrict__ out) {
    __shared__ __align__(16) float m_l[8 * 268];
    __shared__ __align__(16) float h2_l[8 * 92];
    const int t = threadIdx.x;
    const int r0 = blockIdx.x * 8;
    const bool act = (t < 264);
    const int rb = (t & 3) * 2;
    const int cb = (t >> 2) * 4;

    for (int idx = t; idx < 8 * MID; idx += 320) {
        const int r = idx / MID, c = idx - r * MID;
        const float gv = g64[(size_t)r0 * MID + idx] * 0.015625f;
        m_l[r * 268 + c] = fmaxf(10.f * gv, 0.f);
    }
    float gr[2][4], ur[2][4];
    if (act) {
#pragma unroll
        for (int u = 0; u < 2; ++u) {
            const float4 gq = *(const float4*)&g64[(size_t)(r0 + rb + u) * MID + cb];
            gr[u][0] = gq.x * 0.015625f; gr[u][1] = gq.y * 0.015625f;
            gr[u][2] = gq.z * 0.015625f; gr[u][3] = gq.w * 0.015625f;
#pragma unroll
            for (int j = 0; j < 4; ++j) ur[u][j] = -gr[u][j];
        }
    }
    __syncthreads();

    for (int it = 0; it < 4; ++it) {
        float v[2][4];
        if (act) {
#pragma unroll
            for (int u = 0; u < 2; ++u)
#pragma unroll
                for (int j = 0; j < 4; ++j) v[u][j] = 0.f;
            for (int k = 0; k < MID; k += 4) {
                float4 m4[2];
#pragma unroll
                for (int u = 0; u < 2; ++u) m4[u] = *(const float4*)&m_l[(rb + u) * 268 + k];
#pragma unroll
                for (int j = 0; j < 4; ++j) {
                    const float4 gv4 = *(const float4*)&Gm[(size_t)(cb + j) * MID + k];
#pragma unroll
                    for (int u = 0; u < 2; ++u)
                        v[u][j] += m4[u].x * gv4.x + m4[u].y * gv4.y + m4[u].z * gv4.z + m4[u].w * gv4.w;
                }
            }
        }
        __syncthreads();
        if (act) {
#pragma unroll
            for (int u = 0; u < 2; ++u)
#pragma unroll
                for (int j = 0; j < 4; ++j) {
                    const float un = 1.6f * (v[u][j] - gr[u][j]) + 0.2f * ur[u][j];
                    ur[u][j] = un;
                    float* mp = &m_l[(rb + u) * 268 + cb + j];
                    *mp = fmaxf(-8.f * un + 0.2f * (*mp), 0.f);
                }
        }
        __syncthreads();
    }

    {
        float v[2][4];
        if (act) {
#pragma unroll
            for (int u = 0; u < 2; ++u)
#pragma unroll
                for (int j = 0; j < 4; ++j) v[u][j] = 0.f;
            for (int k = 0; k < MID; k += 4) {
                float4 m4[2];
#pragma unroll
                for (int u = 0; u < 2; ++u) m4[u] = *(const float4*)&m_l[(rb + u) * 268 + k];
#pragma unroll
                for (int j = 0; j < 4; ++j) {
                    const float4 wv = *(const float4*)&W1[(size_t)(cb + j) * MID + k];
#pragma unroll
                    for (int u = 0; u < 2; ++u)
                        v[u][j] += m4[u].x * wv.x + m4[u].y * wv.y + m4[u].z * wv.z + m4[u].w * wv.w;
                }
            }
        }
        __syncthreads();
        if (act) {
#pragma unroll
            for (int u = 0; u < 2; ++u)
#pragma unroll
                for (int j = 0; j < 4; ++j)
                    m_l[(rb + u) * 268 + cb + j] = fmaxf(v[u][j] + b1[cb + j], 0.f);
        }
        __syncthreads();
    }

    const bool act2 = (t < 88);
    const int rb2 = (t & 3) * 2, cb2 = (t >> 2) * 4;
    if (act2) {
        float v[2][4];
#pragma unroll
        for (int u = 0; u < 2; ++u)
#pragma unroll
            for (int j = 0; j < 4; ++j) v[u][j] = 0.f;
        for (int k = 0; k < MID; k += 4) {
            float4 m4[2];
#pragma unroll
            for (int u = 0; u < 2; ++u) m4[u] = *(const float4*)&m_l[(rb2 + u) * 268 + k];
#pragma unroll
            for (int j = 0; j < 4; ++j) {
                const float4 wv = *(const float4*)&W2[(size_t)(cb2 + j) * MID + k];
#pragma unroll
                for (int u = 0; u < 2; ++u)
                    v[u][j] += m4[u].x * wv.x + m4[u].y * wv.y + m4[u].z * wv.z + m4[u].w * wv.w;
            }
        }
#pragma unroll
        for (int u = 0; u < 2; ++u)
#pragma unroll
            for (int j = 0; j < 4; ++j)
                h2_l[(rb2 + u) * 92 + cb2 + j] = fmaxf(v[u][j] + b2[cb2 + j], 0.f);
    }
    __syncthreads();
    if (act2) {
        float v[2][4];
#pragma unroll
        for (int u = 0; u < 2; ++u)
#pragma unroll
            for (int j = 0; j < 4; ++j) v[u][j] = 0.f;
        for (int q = 0; q < PD; q += 4) {
            float4 h4[2];
#pragma unroll
            for (int u = 0; u < 2; ++u) h4[u] = *(const float4*)&h2_l[(rb2 + u) * 92 + q];
#pragma unroll
            for (int j = 0; j < 4; ++j) {
                const float4 wv = *(const float4*)&Wout[(size_t)(cb2 + j) * PD + q];
#pragma unroll
                for (int u = 0; u < 2; ++u)
                    v[u][j] += h4[u].x * wv.x + h4[u].y * wv.y + h4[u].z * wv.z + h4[u].w * wv.w;
            }
        }
#pragma unroll
        for (int u = 0; u < 2; ++u) {
            float4 o;
            o.x = 1.f / (1.f + expf(-(v[u][0] + bout[cb2 + 0])));
            o.y = 1.f / (1.f + expf(-(v[u][1] + bout[cb2 + 1])));
            o.z = 1.f / (1.f + expf(-(v[u][2] + bout[cb2 + 2])));
            o.w = 1.f / (1.f + expf(-(v[u][3] + bout[cb2 + 3])));
            *(float4*)&out[(size_t)(r0 + rb2 + u) * PD + cb2] = o;
        }
    }
}

extern "C" void kernel_launch(void* const* d_in, const int* in_sizes, int n_in,
                              void* d_out, int out_size, void* d_ws, size_t ws_size,
                              hipStream_t stream) {
    (void)in_sizes; (void)n_in; (void)out_size; (void)ws_size;
    const float* inp  = (const float*)d_in[0];
    const float* wcos = (const float*)d_in[2];
    const float* wsin = (const float*)d_in[3];
    const float* tmpl = (const float*)d_in[4];
    const float* W1   = (const float*)d_in[5];
    const float* b1   = (const float*)d_in[6];
    const float* W2   = (const float*)d_in[7];
    const float* b2   = (const float*)d_in[8];
    const float* Wout = (const float*)d_in[9];
    const float* bout = (const float*)d_in[10];
    float* out = (float*)d_out;

    char* p = (char*)d_ws;
    f16* a_h    = (f16*)p;   p += (size_t)B_SZ * KLEN * 2;
    f16* wc_h   = (f16*)p;   p += (size_t)NF * KLEN * 2;
    f16* ws_h   = (f16*)p;   p += (size_t)NF * KLEN * 2;
    f16* feat_h = (f16*)p;   p += (size_t)B_SZ * NF * 2;
    f16* tt_h   = (f16*)p;   p += (size_t)320 * NF * 2;
    float* alpha= (float*)p; p += (size_t)B_SZ * 4;
    float* g64  = (float*)p; p += (size_t)B_SZ * MID * 4;
    float* Gm   = (float*)p; p += (size_t)MID * MID * 4;

    hipMemsetAsync(Gm, 0, (size_t)MID * MID * 4, stream);
    k_row_prep<<<B_SZ, 256, 0, stream>>>(inp, a_h, alpha);
    k_cvt_w2<<<dim3(2048, 2), 256, 0, stream>>>(wcos, wsin, wc_h, ws_h,
                                                (int)((size_t)NF * KLEN / 4));
    k_prep_tt<<<dim3(NF / 32, 10), 256, 0, stream>>>(tmpl, tt_h);
    k_gram<<<dim3(5, 5, 6), 256, 0, stream>>>(tmpl, Gm);
    k_fourier<<<dim3(NF / 64, B_SZ / 128), 256, 0, stream>>>(a_h, wc_h, ws_h, alpha, feat_h);
    k_ggemm<<<dim3(5, B_SZ / 128), 256, 0, stream>>>(feat_h, tt_h, g64);
    k_tail<<<B_SZ / 8, 320, 0, stream>>>(g64, Gm, W1, b1, W2, b2, Wout, bout, out);
}